// Round 15
// baseline (30.563 us; speedup 1.0000x reference)
//
#include <hip/hip_runtime.h>
#include <math.h>

// Problem constants
constexpr int NT = 32;     // components
constexpr int ND = 1024;   // dim
constexpr int NB = 4096;   // batch
constexpr int NBLK_MAIN = 512;   // k_main grid

typedef float f2 __attribute__((ext_vector_type(2)));

// Workspace layout (float offsets)
//  ivc : [256][32][4] chunk-major inv_var            @ 0       (32768)
//  m2c : [256][32][4] chunk-major (-2*mu*inv_var)    @ 32768   (32768)
//  c2  : [32]  sum(mu^2*inv_var)                     @ 65536   (32)
//  klg : [B][T]                                      @ 65600   (131072)
//  lpi : [B][T]                                      @ 196672  (131072)
//  Pg  : [512][32] per-block partial sum klg         @ 327744  (16384)
//  Pp  : [512][32] per-block partial sum lpi         @ 344128  (16384)
constexpr int OFF_M2C = 32768;
constexpr int OFF_C2  = 65536;
constexpr int OFF_KLG = 65600;
constexpr int OFF_LPI = 196672;
constexpr int OFF_PG  = 327744;
constexpr int OFF_PP  = 344128;

// ---------------------------------------------------------------------------
// Kernel A: per-component stats + zero out[0].
// grid = 32 (one block per component t), block = 256.
// ---------------------------------------------------------------------------
__global__ __launch_bounds__(256) void k_stats(const float* __restrict__ mu,
                                               const float* __restrict__ rho,
                                               float* __restrict__ ws,
                                               float* __restrict__ out) {
  float* ivc = ws;
  float* m2c = ws + OFF_M2C;
  float* c2  = ws + OFF_C2;

  const int t = blockIdx.x;
  const int c = threadIdx.x;  // chunk index 0..255 (covers d = 4c..4c+3)

  float4 mu4  = reinterpret_cast<const float4*>(mu  + t * ND)[c];
  float4 rho4 = reinterpret_cast<const float4*>(rho + t * ND)[c];

  float rr[4] = {rho4.x, rho4.y, rho4.z, rho4.w};
  float mm[4] = {mu4.x,  mu4.y,  mu4.z,  mu4.w};
  float iv[4], m2[4];
  float c2p = 0.0f;
#pragma unroll
  for (int j = 0; j < 4; ++j) {
    float sd  = log1pf(expf(rr[j]));   // softplus
    float ivv = 1.0f / (sd * sd);
    iv[j] = ivv;
    m2[j] = -2.0f * mm[j] * ivv;
    c2p  += mm[j] * mm[j] * ivv;
  }
  float4 iv4 = {iv[0], iv[1], iv[2], iv[3]};
  float4 m24 = {m2[0], m2[1], m2[2], m2[3]};
  reinterpret_cast<float4*>(ivc)[c * NT + t] = iv4;   // chunk-major
  reinterpret_cast<float4*>(m2c)[c * NT + t] = m24;

#pragma unroll
  for (int m = 32; m >= 1; m >>= 1) c2p += __shfl_xor(c2p, m, 64);
  __shared__ float red[4];
  const int wave = threadIdx.x >> 6, lane = threadIdx.x & 63;
  if (lane == 0) red[wave] = c2p;
  __syncthreads();
  if (threadIdx.x == 0) {
    c2[t] = red[0] + red[1] + red[2] + red[3];
    if (t == 0) out[0] = 0.0f;   // must re-zero every launch (graph replays)
  }
}

// ---------------------------------------------------------------------------
// Kernel B v12: r8 structure with (1) LDS natively typed float4 -> forces
// 16-B-aligned ds_read_b128/ds_write_b128 (r11's VALU-busy was ~2x the
// source-level instruction count: the float->float4 reinterpret LDS reads
// scalarizing to ds_read_b32 x4 is the matching culprit), and (2) packed
// f32 FMA (v_pk_fma_f32) halving FMA issue slots.
// grid = 512 blocks x 512 threads (8 waves, 40 KB LDS, ~4 blocks/CU).
// ---------------------------------------------------------------------------
__global__ __launch_bounds__(512, 4) void k_main(const float* __restrict__ x,
                                                 const float* __restrict__ beta,
                                                 float* __restrict__ ws) {
  const float* ivc = ws;
  const float* m2c = ws + OFF_M2C;
  const float* c2  = ws + OFF_C2;
  float* klg = ws + OFF_KLG;
  float* lpi = ws + OFF_LPI;
  float* Pg  = ws + OFF_PG;
  float* Pp  = ws + OFF_PP;

  const int tid  = threadIdx.x;
  const int q    = tid >> 6;        // wave = d-eighth (0..7)
  const int lane = tid & 63;
  const int h = lane >> 5, t = lane & 31;
  const int row0 = blockIdx.x * 8;

  __shared__ float4 xs4[8 * 256];   // 32 KB, natively float4 (16-B aligned)
  __shared__ float part[8][8][32];  // 8 KB

  // ---- Stage x (coalesced, block-wide): typed float4 ds_write_b128 ----
  {
    const float4* xg4 = reinterpret_cast<const float4*>(x) + (size_t)row0 * 256;
#pragma unroll
    for (int k = 0; k < 4; ++k) {
      xs4[k * 512 + tid] = xg4[k * 512 + tid];
    }
  }
  __syncthreads();

  // ---- FMA loop: x from LDS (typed b128 broadcast), iv/m2 from L2 ----
  // chunk c = q*32 + h*16 + i (i=0..15); float4 idx = c*32 + t (chunk-major)
  const int c0 = q * 32 + h * 16;
  const float4* ivp = reinterpret_cast<const float4*>(ivc) + (size_t)c0 * NT + t;
  const float4* m2p = reinterpret_cast<const float4*>(m2c) + (size_t)c0 * NT + t;
  const float4* xsp = xs4 + c0;

  f2 a2[8];
#pragma unroll
  for (int r = 0; r < 8; ++r) a2[r] = (f2){0.f, 0.f};

#pragma unroll 4
  for (int i = 0; i < 16; ++i) {
    float4 iv4 = ivp[(size_t)i * NT];
    float4 m24 = m2p[(size_t)i * NT];
    const f2 ivl = {iv4.x, iv4.y}, ivh = {iv4.z, iv4.w};
    const f2 ml  = {m24.x, m24.y}, mh  = {m24.z, m24.w};
#pragma unroll
    for (int r = 0; r < 8; ++r) {
      float4 xv = xsp[r * 256 + i];   // typed ds_read_b128 (broadcast)
      const f2 xl = {xv.x, xv.y}, xh = {xv.z, xv.w};
      // acc += x*(x*iv + m2), two packed halves (v_pk_fma_f32 x4)
      a2[r] = __builtin_elementwise_fma(xl, __builtin_elementwise_fma(xl, ivl, ml), a2[r]);
      a2[r] = __builtin_elementwise_fma(xh, __builtin_elementwise_fma(xh, ivh, mh), a2[r]);
    }
  }
  // horizontal + combine the two 64-d sub-halves within the wave
#pragma unroll
  for (int r = 0; r < 8; ++r) {
    float s = a2[r].x + a2[r].y;
    s += __shfl_xor(s, 32, 64);
    if (h == 0) part[q][r][t] = s;
  }
  __syncthreads();

  // ---- Epilogue on first 4 waves: rr = row-in-block, t2 = component ----
  const int rr = tid >> 5, t2 = tid & 31;
  float kv = 0.f, lp = 0.f;
  if (tid < 256) {
    float quad = 0.f;
#pragma unroll
    for (int qq = 0; qq < 8; ++qq) quad += part[qq][rr][t2];
    // kl_gaussian = log_pdfs + entropy = D/2 - 0.5*quad (log_std_sum cancels)
    kv = 512.0f - 0.5f * (quad + c2[t2]);
    klg[(size_t)(row0 + rr) * NT + t2] = kv;

    // log_pi: exclusive prefix scan of log1p(-beta) within each 32-lane group
    const float b = beta[(size_t)(row0 + rr) * NT + t2];
    const float l1m = log1pf(-b);
    float s = l1m;
#pragma unroll
    for (int d = 1; d < 32; d <<= 1) {
      float v = __shfl_up(s, (unsigned)d, 32);
      if (t2 >= d) s += v;
    }
    lp = logf(b) + (s - l1m);   // exclusive prefix + log(beta)
    lpi[(size_t)(row0 + rr) * NT + t2] = lp;
  }
  __syncthreads();                 // all part reads done before reuse
  if (tid < 256) {
    part[0][rr][t2] = kv;          // reuse part as reduce scratch
    part[1][rr][t2] = lp;
  }
  __syncthreads();
  if (tid < 32) {
    float sg = 0.f, sp = 0.f;
#pragma unroll
    for (int r = 0; r < 8; ++r) { sg += part[0][r][tid]; sp += part[1][r][tid]; }
    // plain coalesced stores -- no atomics
    Pg[(size_t)blockIdx.x * NT + tid] = sg;
    Pp[(size_t)blockIdx.x * NT + tid] = sp;
  }
}

// ---------------------------------------------------------------------------
// Kernel D: redundant per-block reduce of Pg/Pp (no contended atomics), then
// mix, softmax over T, weighted mean.
// grid = 256, block = 512 (8 waves; 16 rows/block, one per 32-lane group)
// ---------------------------------------------------------------------------
__global__ __launch_bounds__(512) void k_final(const float* __restrict__ ws,
                                               float* __restrict__ out) {
  const float* klg = ws + OFF_KLG;
  const float* lpi = ws + OFF_LPI;
  const float* Pg  = ws + OFF_PG;
  const float* Pp  = ws + OFF_PP;

  const int tid  = threadIdx.x;
  const int wave = tid >> 6, lane = tid & 63;
  const int t = tid & 31;        // component
  const int g = tid >> 5;        // reduce group 0..15 / row-in-block

  __shared__ float ngF[32], npF[32];
  __shared__ float redG[8][32], redP[8][32];
  __shared__ float red[8];

  // ---- Prologue: reduce the 512 per-block partials (redundant) ----
  {
    float sg = 0.f, sp = 0.f;
#pragma unroll 8
    for (int b = g; b < NBLK_MAIN; b += 16) {
      sg += Pg[(size_t)b * NT + t];
      sp += Pp[(size_t)b * NT + t];
    }
    sg += __shfl_xor(sg, 32, 64);
    sp += __shfl_xor(sp, 32, 64);
    if (lane < 32) { redG[wave][t] = sg; redP[wave][t] = sp; }
  }
  __syncthreads();
  if (tid < 32) {
    float ng = 0.f, np = 0.f;
#pragma unroll
    for (int w = 0; w < 8; ++w) { ng += redG[w][tid]; np += redP[w][tid]; }
    ngF[tid] = ng;
    npF[tid] = np;
  }
  __syncthreads();

  // ---- mix + softmax over T + weighted mean ----
  const int row = blockIdx.x * 16 + g;
  const float kg = klg[(size_t)row * NT + t];
  const float lp = lpi[(size_t)row * NT + t];
  const float ng = ngF[t], np = npF[t];
  const float mix  = np / (ng + np);
  const float klgm = mix * kg;
  const float kl   = klgm + (1.0f - mix) * lp;

  float m = kl;
#pragma unroll
  for (int mk = 16; mk >= 1; mk >>= 1) m = fmaxf(m, __shfl_xor(m, mk, 64));
  const float e = expf(kl - m);
  float num = e * klgm, den = e;
#pragma unroll
  for (int mk = 16; mk >= 1; mk >>= 1) {
    num += __shfl_xor(num, mk, 64);
    den += __shfl_xor(den, mk, 64);
  }
  float s = num / den;           // per-row sum_t phi*klgm (replicated in group)
  s += __shfl_xor(s, 32, 64);    // combine the wave's two rows

  if (lane == 0) red[wave] = s;
  __syncthreads();
  if (tid == 0) {
    float tot = 0.f;
#pragma unroll
    for (int w = 0; w < 8; ++w) tot += red[w];
    atomicAdd(out, tot * (1.0f / (float)NB));
  }
}

// ---------------------------------------------------------------------------
extern "C" void kernel_launch(void* const* d_in, const int* in_sizes, int n_in,
                              void* d_out, int out_size, void* d_ws, size_t ws_size,
                              hipStream_t stream) {
  const float* x    = (const float*)d_in[0];
  const float* mu   = (const float*)d_in[1];
  const float* rho  = (const float*)d_in[2];
  const float* beta = (const float*)d_in[3];
  float* out = (float*)d_out;
  float* ws  = (float*)d_ws;

  hipLaunchKernelGGL(k_stats, dim3(32),        dim3(256), 0, stream, mu, rho, ws, out);
  hipLaunchKernelGGL(k_main,  dim3(NBLK_MAIN), dim3(512), 0, stream, x, beta, ws);
  hipLaunchKernelGGL(k_final, dim3(256),       dim3(512), 0, stream, ws, out);
}

// Round 16
// 30.173 us; speedup vs baseline: 1.0129x; 1.0129x over previous
//
#include <hip/hip_runtime.h>
#include <math.h>

// Problem constants
constexpr int NT = 32;     // components
constexpr int ND = 1024;   // dim
constexpr int NB = 4096;   // batch
constexpr int NBLK_MAIN = 256;   // k_main grid (16 rows/block)

typedef short bf16x8 __attribute__((ext_vector_type(8)));
typedef float f32x4  __attribute__((ext_vector_type(4)));

// Workspace layout (float offsets)
//  Bh : [32][2048] bf16 (iv,m2 interleaved, hi)   @ 0       (32768 floats)
//  Bl : [32][2048] bf16 (lo residual)             @ 32768   (32768)
//  c2 : [32]                                      @ 65536
//  klg: [B][T]                                    @ 65600   (131072)
//  lpi: [B][T]                                    @ 196672  (131072)
//  Pg : [256][32] per-block partial sum klg       @ 327744  (8192)
//  Pp : [256][32] per-block partial sum lpi       @ 335936  (8192)
constexpr int OFF_C2  = 65536;
constexpr int OFF_KLG = 65600;
constexpr int OFF_LPI = 196672;
constexpr int OFF_PG  = 327744;
constexpr int OFF_PP  = 335936;

// round-to-nearest-even f32 -> bf16 (as ushort) and back
__device__ __forceinline__ unsigned short bf16h(float x) {
  unsigned u = __float_as_uint(x);
  u = u + 0x7FFFu + ((u >> 16) & 1u);
  return (unsigned short)(u >> 16);
}
__device__ __forceinline__ float bf16f(unsigned short h) {
  return __uint_as_float(((unsigned)h) << 16);
}

// ---------------------------------------------------------------------------
// Kernel A: build B-matrices in bf16 hi/lo split + c2 + zero out[0].
// B[t][2d] = iv[t][d], B[t][2d+1] = m2[t][d]; Bh = bf16(B), Bl = bf16(B-Bh).
// grid = 32 (block per t), block = 256 (thread c covers d = 4c..4c+3).
// ---------------------------------------------------------------------------
__global__ __launch_bounds__(256) void k_stats(const float* __restrict__ mu,
                                               const float* __restrict__ rho,
                                               float* __restrict__ ws,
                                               float* __restrict__ out) {
  unsigned short* Bh = reinterpret_cast<unsigned short*>(ws);
  unsigned short* Bl = Bh + 65536;
  float* c2 = ws + OFF_C2;

  const int t = blockIdx.x;
  const int c = threadIdx.x;

  float4 mu4 = reinterpret_cast<const float4*>(mu  + t * ND)[c];
  float4 rh4 = reinterpret_cast<const float4*>(rho + t * ND)[c];
  float mm[4] = {mu4.x, mu4.y, mu4.z, mu4.w};
  float rr[4] = {rh4.x, rh4.y, rh4.z, rh4.w};

  bf16x8 hv, lv;
  float c2p = 0.0f;
#pragma unroll
  for (int j = 0; j < 4; ++j) {
    float sd  = log1pf(expf(rr[j]));   // softplus
    float ivv = 1.0f / (sd * sd);
    float m2v = -2.0f * mm[j] * ivv;
    c2p += mm[j] * mm[j] * ivv;
    unsigned short ih = bf16h(ivv);
    unsigned short il = bf16h(ivv - bf16f(ih));
    unsigned short mh = bf16h(m2v);
    unsigned short ml = bf16h(m2v - bf16f(mh));
    hv[2 * j] = (short)ih; hv[2 * j + 1] = (short)mh;
    lv[2 * j] = (short)il; lv[2 * j + 1] = (short)ml;
  }
  *reinterpret_cast<bf16x8*>(Bh + (size_t)t * 2048 + c * 8) = hv;
  *reinterpret_cast<bf16x8*>(Bl + (size_t)t * 2048 + c * 8) = lv;

#pragma unroll
  for (int m = 32; m >= 1; m >>= 1) c2p += __shfl_xor(c2p, m, 64);
  __shared__ float red[4];
  const int wave = threadIdx.x >> 6, lane = threadIdx.x & 63;
  if (lane == 0) red[wave] = c2p;
  __syncthreads();
  if (threadIdx.x == 0) {
    c2[t] = red[0] + red[1] + red[2] + red[3];
    if (t == 0) out[0] = 0.0f;   // re-zero every launch (graph replays)
  }
}

// ---------------------------------------------------------------------------
// Kernel B v13: MFMA bf16-split GEMM. quad = A.B^T, A[b][2d,2d+1]=(x^2,x),
// B[t][2d,2d+1]=(iv,m2); 2-way bf16 split: AhBh + AhBl + AlBh accumulated
// in one f32 acc (dropped AlBl ~2^-18 rel). Replaces the LDS-broadcast
// delivery path (measured floor ~5cy/16B-segment -> 8.5us) with coalesced
// MFMA fragment reads (~85 B/cy).
// grid = 256 blocks x 512 threads (8 waves; 1 block/CU). Block owns 16 rows
// (one M-frag); waves split K (wave w: 64 k per 512-k slice; 4 slices).
// Per slice: all threads stage x->convert->Ah/Al LDS; waves then run
// 2 k-steps x 6 MFMAs with B-frags loaded straight from global (B = 256 KB,
// L2-resident, reused by all blocks). C-layout (m89): col=lane&15,
// row=(lane>>4)*4+reg. A: lane=row+16*(k/8),elem=k%8; B symmetric.
// ---------------------------------------------------------------------------
__global__ __launch_bounds__(512) void k_main(const float* __restrict__ x,
                                              const float* __restrict__ beta,
                                              float* __restrict__ ws) {
  const unsigned short* Bh = reinterpret_cast<const unsigned short*>(ws);
  const unsigned short* Bl = Bh + 65536;
  const float* c2 = ws + OFF_C2;
  float* klg = ws + OFF_KLG;
  float* lpi = ws + OFF_LPI;
  float* Pg  = ws + OFF_PG;
  float* Pp  = ws + OFF_PP;

  const int tid  = threadIdx.x;
  const int w    = tid >> 6;         // wave 0..7 (K-splitter)
  const int lane = tid & 63;
  const int l15  = lane & 15;        // fragment row/col
  const int g4   = lane >> 4;        // fragment k-group 0..3
  const int row0 = blockIdx.x * 16;

  __shared__ __align__(16) short Ah[16 * 520];  // [row][k_local], +8 pad
  __shared__ __align__(16) short Al[16 * 520];
  __shared__ float part[8][16][32];             // 16 KB

  // stage mapping: thread = (srow, dch); covers 8 d's per slice
  const int srow = tid >> 5;         // 0..15
  const int dch  = tid & 31;         // 0..31
  const float4* xr4 =
      reinterpret_cast<const float4*>(x + (size_t)(row0 + srow) * ND) + dch * 2;

  float4 xa = xr4[0], xb = xr4[1];   // slice 0 preload (d = dch*8..+7)

  f32x4 acc0 = {0.f, 0.f, 0.f, 0.f};  // t 0..15
  f32x4 acc1 = {0.f, 0.f, 0.f, 0.f};  // t 16..31

#pragma unroll
  for (int s = 0; s < 4; ++s) {
    __syncthreads();   // previous slice's A-frag reads complete
    // ---- convert & store this slice's A (k_local = dch*16 + 2j + {0,1}) --
    {
      float xv[8] = {xa.x, xa.y, xa.z, xa.w, xb.x, xb.y, xb.z, xb.w};
      bf16x8 h0, h1, lo0, lo1;
#pragma unroll
      for (int j = 0; j < 8; ++j) {
        float sq = xv[j] * xv[j];
        unsigned short sh = bf16h(sq);
        unsigned short sl = bf16h(sq - bf16f(sh));
        unsigned short xh = bf16h(xv[j]);
        unsigned short xl = bf16h(xv[j] - bf16f(xh));
        if (j < 4) {
          h0[2 * j] = (short)sh;  h0[2 * j + 1] = (short)xh;
          lo0[2 * j] = (short)sl; lo0[2 * j + 1] = (short)xl;
        } else {
          h1[2 * (j - 4)] = (short)sh;  h1[2 * (j - 4) + 1] = (short)xh;
          lo1[2 * (j - 4)] = (short)sl; lo1[2 * (j - 4) + 1] = (short)xl;
        }
      }
      const int ab = srow * 520 + dch * 16;
      *reinterpret_cast<bf16x8*>(&Ah[ab])     = h0;
      *reinterpret_cast<bf16x8*>(&Ah[ab + 8]) = h1;
      *reinterpret_cast<bf16x8*>(&Al[ab])     = lo0;
      *reinterpret_cast<bf16x8*>(&Al[ab + 8]) = lo1;
    }
    if (s < 3) { xa = xr4[(s + 1) * 64]; xb = xr4[(s + 1) * 64 + 1]; }
    __syncthreads();   // A slice ready

    // ---- MFMA: wave w covers k_local in [w*64, w*64+64) ----
#pragma unroll
    for (int st = 0; st < 2; ++st) {
      const int kl = w * 64 + st * 32 + g4 * 8;   // k_local (frag base)
      const int kg = s * 512 + kl;                // absolute k for B
      bf16x8 afh = *reinterpret_cast<const bf16x8*>(&Ah[l15 * 520 + kl]);
      bf16x8 afl = *reinterpret_cast<const bf16x8*>(&Al[l15 * 520 + kl]);
      bf16x8 bh0 = *reinterpret_cast<const bf16x8*>(Bh + (size_t)l15 * 2048 + kg);
      bf16x8 bh1 = *reinterpret_cast<const bf16x8*>(Bh + (size_t)(16 + l15) * 2048 + kg);
      bf16x8 bl0 = *reinterpret_cast<const bf16x8*>(Bl + (size_t)l15 * 2048 + kg);
      bf16x8 bl1 = *reinterpret_cast<const bf16x8*>(Bl + (size_t)(16 + l15) * 2048 + kg);
      acc0 = __builtin_amdgcn_mfma_f32_16x16x32_bf16(afh, bh0, acc0, 0, 0, 0);
      acc1 = __builtin_amdgcn_mfma_f32_16x16x32_bf16(afh, bh1, acc1, 0, 0, 0);
      acc0 = __builtin_amdgcn_mfma_f32_16x16x32_bf16(afh, bl0, acc0, 0, 0, 0);
      acc1 = __builtin_amdgcn_mfma_f32_16x16x32_bf16(afh, bl1, acc1, 0, 0, 0);
      acc0 = __builtin_amdgcn_mfma_f32_16x16x32_bf16(afl, bh0, acc0, 0, 0, 0);
      acc1 = __builtin_amdgcn_mfma_f32_16x16x32_bf16(afl, bh1, acc1, 0, 0, 0);
    }
  }

  // ---- C-fragment -> part: row=(lane>>4)*4+v, col=lane&15 (m89) ----
  {
    const int crow = g4 * 4;
#pragma unroll
    for (int v = 0; v < 4; ++v) {
      part[w][crow + v][l15]      = acc0[v];
      part[w][crow + v][16 + l15] = acc1[v];
    }
  }
  __syncthreads();

  // ---- Epilogue: 512 threads = (row rr, t t2) ----
  const int rr = tid >> 5, t2 = tid & 31;
  float quad = 0.f;
#pragma unroll
  for (int ww = 0; ww < 8; ++ww) quad += part[ww][rr][t2];
  // kl_gaussian = log_pdfs + entropy = D/2 - 0.5*(quad + c2) (log_std cancels)
  const float kv = 512.0f - 0.5f * (quad + c2[t2]);
  klg[(size_t)(row0 + rr) * NT + t2] = kv;

  // log_pi: exclusive prefix scan of log1p(-beta) within each 32-lane group
  const float b = beta[(size_t)(row0 + rr) * NT + t2];
  const float l1m = log1pf(-b);
  float sc = l1m;
#pragma unroll
  for (int d = 1; d < 32; d <<= 1) {
    float v = __shfl_up(sc, (unsigned)d, 32);
    if (t2 >= d) sc += v;
  }
  const float lp = logf(b) + (sc - l1m);
  lpi[(size_t)(row0 + rr) * NT + t2] = lp;

  __syncthreads();                 // part reads done before reuse
  part[0][rr][t2] = kv;
  part[1][rr][t2] = lp;
  __syncthreads();
  if (tid < 32) {
    float sg = 0.f, sp = 0.f;
#pragma unroll
    for (int r = 0; r < 16; ++r) { sg += part[0][r][tid]; sp += part[1][r][tid]; }
    Pg[(size_t)blockIdx.x * NT + tid] = sg;   // plain stores, no atomics
    Pp[(size_t)blockIdx.x * NT + tid] = sp;
  }
}

// ---------------------------------------------------------------------------
// Kernel D: redundant per-block reduce of Pg/Pp, then mix/softmax/mean.
// grid = 256, block = 512 (16 rows/block, one per 32-lane group).
// ---------------------------------------------------------------------------
__global__ __launch_bounds__(512) void k_final(const float* __restrict__ ws,
                                               float* __restrict__ out) {
  const float* klg = ws + OFF_KLG;
  const float* lpi = ws + OFF_LPI;
  const float* Pg  = ws + OFF_PG;
  const float* Pp  = ws + OFF_PP;

  const int tid  = threadIdx.x;
  const int wave = tid >> 6, lane = tid & 63;
  const int t = tid & 31;
  const int g = tid >> 5;

  __shared__ float ngF[32], npF[32];
  __shared__ float redG[8][32], redP[8][32];
  __shared__ float red[8];

  {
    float sg = 0.f, sp = 0.f;
#pragma unroll 4
    for (int b = g; b < NBLK_MAIN; b += 16) {
      sg += Pg[(size_t)b * NT + t];
      sp += Pp[(size_t)b * NT + t];
    }
    sg += __shfl_xor(sg, 32, 64);
    sp += __shfl_xor(sp, 32, 64);
    if (lane < 32) { redG[wave][t] = sg; redP[wave][t] = sp; }
  }
  __syncthreads();
  if (tid < 32) {
    float ng = 0.f, np = 0.f;
#pragma unroll
    for (int w = 0; w < 8; ++w) { ng += redG[w][tid]; np += redP[w][tid]; }
    ngF[tid] = ng;
    npF[tid] = np;
  }
  __syncthreads();

  const int row = blockIdx.x * 16 + g;
  const float kg = klg[(size_t)row * NT + t];
  const float lp = lpi[(size_t)row * NT + t];
  const float ng = ngF[t], np = npF[t];
  const float mix  = np / (ng + np);
  const float klgm = mix * kg;
  const float kl   = klgm + (1.0f - mix) * lp;

  float m = kl;
#pragma unroll
  for (int mk = 16; mk >= 1; mk >>= 1) m = fmaxf(m, __shfl_xor(m, mk, 64));
  const float e = expf(kl - m);
  float num = e * klgm, den = e;
#pragma unroll
  for (int mk = 16; mk >= 1; mk >>= 1) {
    num += __shfl_xor(num, mk, 64);
    den += __shfl_xor(den, mk, 64);
  }
  float s = num / den;
  s += __shfl_xor(s, 32, 64);

  if (lane == 0) red[wave] = s;
  __syncthreads();
  if (tid == 0) {
    float tot = 0.f;
#pragma unroll
    for (int w = 0; w < 8; ++w) tot += red[w];
    atomicAdd(out, tot * (1.0f / (float)NB));
  }
}

// ---------------------------------------------------------------------------
extern "C" void kernel_launch(void* const* d_in, const int* in_sizes, int n_in,
                              void* d_out, int out_size, void* d_ws, size_t ws_size,
                              hipStream_t stream) {
  const float* x    = (const float*)d_in[0];
  const float* mu   = (const float*)d_in[1];
  const float* rho  = (const float*)d_in[2];
  const float* beta = (const float*)d_in[3];
  float* out = (float*)d_out;
  float* ws  = (float*)d_ws;

  hipLaunchKernelGGL(k_stats, dim3(32),        dim3(256), 0, stream, mu, rho, ws, out);
  hipLaunchKernelGGL(k_main,  dim3(NBLK_MAIN), dim3(512), 0, stream, x, beta, ws);
  hipLaunchKernelGGL(k_final, dim3(256),       dim3(512), 0, stream, ws, out);
}